// Round 6
// baseline (225.077 us; speedup 1.0000x reference)
//
#include <hip/hip_runtime.h>
#include <hip/hip_bf16.h>

// RNN: B=1024, T=512, H=128, +4 autoregressive steps -> out (1024, 516)
// Round 17 (resubmit; prior bench was an infra failure, no data).
// R13 restored exactly (proven 154us: ybuf in LDS + end flush,
// per-step b32 x reads) + ONE change: wave-7's dec MFMA moved into the
// READ SHADOW. R16 placed dec BEFORE the ds_read issue (wave 7's reads
// joined the queue late -> still straggler, plus per-step global-store
// vmcnt cost). Here: bfrag is double-set (E/O, compile-time alternation);
// each step issues its 4 ds_read_b128 FIRST, then wave 7 runs dec MFMAs
// on the PREVIOUS step's fragments (registers) + ybuf LDS write while the
// reads drain. Emits y[T-2] (indexing validated in R16).
// Step model (R13=716cy): head latency 120 + drain 32xb128 ~375 + straggler
// tail ~170 + slop. This targets the straggler term only.
// Kept from R13: fixed kf order (no runtime frag indexing -> no scratch),
// W/b/w0 pre-scaled by 2*log2e, phase-batched epilogue, fp16 pipeline +
// XOR-swizzled hbuf + v_cvt_pkrtz packing.

#define BB 1024
#define TT 512
#define HH 128
#define TOUT 516
#define BM 16          // batch rows per block
#define XSTR 513       // xs stride (dwords)
#define YSTR 517       // ybuf stride (dwords)
#define PQS 36         // pq row stride (dwords)
#define TWOLOG2E 2.885390082f

typedef __attribute__((ext_vector_type(8))) _Float16 f16x8;
typedef __attribute__((ext_vector_type(4))) float f32x4;

#define MFMA16(A_, B_, C_) __builtin_amdgcn_mfma_f32_16x16x32_f16(A_, B_, C_, 0, 0, 0)

__global__ void detect_dtype(const void* w, int* flag) {
    const int lane = threadIdx.x;  // 64 threads
    const __hip_bfloat16* p = (const __hip_bfloat16*)w;
    const float v0 = __bfloat162float(p[lane]);
    const float v1 = __bfloat162float(p[64 + lane]);
    const bool bad = !(fabsf(v0) < 100.0f) || !(fabsf(v1) < 100.0f);
    const unsigned long long m = __ballot(bad);
    if (lane == 0) *flag = (__popcll(m) > 4) ? 1 : 0;  // 1 => data is fp32
}

template <bool F32>
__device__ __forceinline__ float ldg(const void* p, int idx) {
    if (F32) return ((const float*)p)[idx];
    return __bfloat162float(((const __hip_bfloat16*)p)[idx]);
}

// sum of pq row [0..31] (16B-aligned)
__device__ __forceinline__ float red32(const float* pqrow) {
    const f32x4* v = (const f32x4*)pqrow;
    const f32x4 s = ((v[0] + v[1]) + (v[2] + v[3])) + ((v[4] + v[5]) + (v[6] + v[7]));
    return (s[0] + s[1]) + (s[2] + s[3]);
}

// One RNN step. T_: timestep; CUR_: h read buffer; BNEW_: bfrag set loaded
// this step; BOLD_: previous step's set (registers) used by the deferred
// dec. DODEC_: wave 7 emits y[T_-2] = dec . BOLD_ into ybuf, issued AFTER
// the ds_reads so the dec MFMAs hide in the read shadow. DOPQ_: lanes
// write decoder partials to pq (tail); READX_: prefetch xs[T_+1]; TAILX_:
// xv from pq reduce (feedback).
// hbuf swizzle: logical 16B-chunk c of row r lives at physical chunk (c^r)&15.
// acc accumulates 2*log2e*z; h = 1 - 2/(exp2(acc)+1).
#define STEP(T_, CUR_, DODEC_, DOPQ_, READX_, TAILX_, BNEW_, BOLD_) do {        \
    _Pragma("unroll")                                                           \
    for (int kf = 0; kf < 4; ++kf)                                              \
        BNEW_[kf] = *(const f16x8*)&hbuf[CUR_][n][((((kf << 2) | q) ^ n) & 15) << 3]; \
    if (isw7 && (DODEC_)) {  /* dec on OLD frags, inside the read shadow */     \
        f32x4 dA0 = (f32x4){0.f, 0.f, 0.f, 0.f};                                \
        f32x4 dA1 = (f32x4){0.f, 0.f, 0.f, 0.f};                                \
        dA0 = MFMA16(wa_d[0], BOLD_[0], dA0);                                   \
        dA1 = MFMA16(wa_d[1], BOLD_[1], dA1);                                   \
        dA0 = MFMA16(wa_d[2], BOLD_[2], dA0);                                   \
        dA1 = MFMA16(wa_d[3], BOLD_[3], dA1);                                   \
        if (q == 0) ybuf[n][(T_) - 2] = dA0[0] + dA1[0] + dbv;                  \
    }                                                                           \
    float xnext = 0.0f;                                                         \
    if (READX_) xnext = xs[n][(T_) + 1];                                        \
    float xv;                                                                   \
    if (TAILX_) xv = red32(&pq[((T_) - 1) & 1][n][0]) + dbv;                    \
    else        xv = xpref;                                                     \
    f32x4 acc0, acc1;                                                           \
    _Pragma("unroll")                                                           \
    for (int r = 0; r < 4; ++r) acc0[r] = fmaf(xv, w0v[r], bsum[r]);            \
    acc1 = (f32x4){0.f, 0.f, 0.f, 0.f};                                         \
    acc0 = MFMA16(wa[0], BNEW_[0], acc0);                                       \
    acc1 = MFMA16(wa[1], BNEW_[1], acc1);                                       \
    acc0 = MFMA16(wa[2], BNEW_[2], acc0);                                       \
    acc1 = MFMA16(wa[3], BNEW_[3], acc1);                                       \
    float zs[4], ex[4], rc[4], hv[4];                                           \
    _Pragma("unroll")                                                           \
    for (int r = 0; r < 4; ++r) zs[r] = acc0[r] + acc1[r];                      \
    _Pragma("unroll")                                                           \
    for (int r = 0; r < 4; ++r) ex[r] = __builtin_amdgcn_exp2f(zs[r]);          \
    _Pragma("unroll")                                                           \
    for (int r = 0; r < 4; ++r) rc[r] = __builtin_amdgcn_rcpf(ex[r] + 1.0f);    \
    _Pragma("unroll")                                                           \
    for (int r = 0; r < 4; ++r) hv[r] = fmaf(-2.0f, rc[r], 1.0f);               \
    float p = 0.0f;                                                             \
    if (DOPQ_) {                                                                \
        _Pragma("unroll")                                                       \
        for (int r = 0; r < 4; ++r) p = fmaf(decv[r], hv[r], p);                \
    }                                                                           \
    uint2 pk;                                                                   \
    pk.x = __builtin_bit_cast(unsigned, __builtin_amdgcn_cvt_pkrtz(hv[0], hv[1])); \
    pk.y = __builtin_bit_cast(unsigned, __builtin_amdgcn_cvt_pkrtz(hv[2], hv[3])); \
    *(uint2*)&hbuf[(CUR_) ^ 1][n][((((2 * wv + (q >> 1)) ^ n) & 15) << 3) + ((q & 1) << 2)] = pk; \
    if (DOPQ_) pq[(T_) & 1][n][wv * 4 + q] = p;                                 \
    if (READX_) xpref = xnext;                                                  \
    __syncthreads();                                                            \
} while (0)

template <bool F32>
__device__ void rnn_body(const void* __restrict__ xg, const void* __restrict__ h0,
                         const void* __restrict__ w0, const void* __restrict__ b0,
                         const void* __restrict__ W,  const void* __restrict__ bw,
                         const void* __restrict__ dw, const void* __restrict__ db,
                         void* __restrict__ out,
                         float (*xs)[XSTR], float (*ybuf)[YSTR],
                         _Float16 (*hbuf)[BM][HH], float (*pq)[BM][PQS])
{
    const int tid  = threadIdx.x;
    const int lane = tid & 63;
    const int wv   = tid >> 6;        // 0..7 (= m-tile index)
    const int q    = lane >> 4;       // 0..3
    const int n    = lane & 15;       // batch col / A-row-in-tile
    const int row0 = blockIdx.x * BM;
    const bool isw7 = (wv == 7);      // wave-uniform

    // stage x (fp32 in LDS)
    for (int idx = tid; idx < BM * TT; idx += 512) {
        const int rr = idx >> 9, t2 = idx & (TT - 1);
        xs[rr][t2] = ldg<F32>(xg, (row0 + rr) * TT + t2);
    }
    // stage h0 as fp16 (swizzled: chunk c of row rr -> (c^rr)&15)
    for (int idx = tid; idx < BM * HH; idx += 512) {
        const int rr = idx >> 7, ii = idx & (HH - 1);
        const int po = ((((ii >> 3) ^ rr) & 15) << 3) + (ii & 7);
        hbuf[0][rr][po] = (_Float16)ldg<F32>(h0, (row0 + rr) * HH + ii);
    }

    // preload W fragments (A-operand: A[m=lane&15][k=q*8+j]) as fp16,
    // PRE-SCALED by 2*log2e so the accumulator is the exp2 argument.
    f16x8 wa[4];
    {
        const int ia = wv * 16 + n;   // W row (output unit)
        #pragma unroll
        for (int kf = 0; kf < 4; ++kf) {
            const int kb = kf * 32 + q * 8;
            f16x8 fr;
            #pragma unroll
            for (int j = 0; j < 8; ++j)
                fr[j] = (_Float16)(TWOLOG2E * ldg<F32>(W, ia * HH + kb + j));
            wa[kf] = fr;
        }
    }
    // dec tile (wave 7): A row 0 = dec_w (UNscaled - operates on h), rows 1..15 = 0
    f16x8 wa_d[4] = {};
    if (isw7) {
        #pragma unroll
        for (int kf = 0; kf < 4; ++kf) {
            const int kb = kf * 32 + q * 8;
            f16x8 fr = {};
            if (n == 0) {
                #pragma unroll
                for (int j = 0; j < 8; ++j) fr[j] = (_Float16)ldg<F32>(dw, kb + j);
            }
            wa_d[kf] = fr;
        }
    }
    // epilogue constants (C-layout rows: i = wv*16 + q*4 + r), pre-scaled
    float bsum[4], w0v[4], decv[4];
    #pragma unroll
    for (int r = 0; r < 4; ++r) {
        const int ic = wv * 16 + q * 4 + r;
        bsum[r] = TWOLOG2E * (ldg<F32>(b0, ic) + ldg<F32>(bw, ic));
        w0v[r]  = TWOLOG2E * ldg<F32>(w0, ic);
        decv[r] = ldg<F32>(dw, ic);
    }
    const float dbv = ldg<F32>(db, 0);

    __syncthreads();

    f16x8 bfragE[4], bfragO[4];        // even/odd step fragment sets
    float xpref = xs[n][0];

    // t = 0,1: no dec yet (y[T-2] would be negative)
    STEP(0, 0, false, false, true, false, bfragE, bfragO);
    STEP(1, 1, false, false, true, false, bfragO, bfragE);
    // t = 2: first dec -> y[0]
    STEP(2, 0, true, false, true, false, bfragE, bfragO);

    // main: t = 3..510 (dec emits y[1..508])
    #pragma unroll 1
    for (int t = 3; t < 510; t += 2) {
        STEP(t,     1, true, false, true, false, bfragO, bfragE);
        STEP(t + 1, 0, true, false, true, false, bfragE, bfragO);
    }

    // t = 511: last x step (xpref from t=510's prefetch); start pq feedback
    STEP(511, 1, true, true, false, false, bfragO, bfragE);

    // tail: t = 512..515, xv = y[t-1] via pq reduce; dec emits y[510..513]
    STEP(512, 0, true, true, false, true, bfragE, bfragO);
    STEP(513, 1, true, true, false, true, bfragO, bfragE);
    STEP(514, 0, true, true, false, true, bfragE, bfragO);
    STEP(515, 1, true, true, false, true, bfragO, bfragE);

    // post: y[514] from bfragO (loaded at t=515, = h_514); y[515] via pq[1]
    if (isw7) {
        f32x4 dA0 = (f32x4){0.f, 0.f, 0.f, 0.f};
        f32x4 dA1 = (f32x4){0.f, 0.f, 0.f, 0.f};
        dA0 = MFMA16(wa_d[0], bfragO[0], dA0);
        dA1 = MFMA16(wa_d[1], bfragO[1], dA1);
        dA0 = MFMA16(wa_d[2], bfragO[2], dA0);
        dA1 = MFMA16(wa_d[3], bfragO[3], dA1);
        if (q == 0) {
            ybuf[n][514] = dA0[0] + dA1[0] + dbv;
            ybuf[n][515] = red32(&pq[1][n][0]) + dbv;
        }
    }
    __syncthreads();

    // flush outputs (coalesced over t)
    for (int rr = 0; rr < BM; ++rr)
        for (int t2 = tid; t2 < TOUT; t2 += 512) {
            const int o = (row0 + rr) * TOUT + t2;
            const float y = ybuf[rr][t2];
            if (F32) ((float*)out)[o] = y;
            else     ((__hip_bfloat16*)out)[o] = __float2bfloat16(y);
        }
}

__global__ __launch_bounds__(512, 2)
void rnn_mfma(const void* __restrict__ xg, const void* __restrict__ h0,
              const void* __restrict__ w0, const void* __restrict__ b0,
              const void* __restrict__ W,  const void* __restrict__ bw,
              const void* __restrict__ dw, const void* __restrict__ db,
              void* __restrict__ out, const int* __restrict__ flag)
{
    __shared__ float xs[BM][XSTR];                          // 32.8 KB
    __shared__ float ybuf[BM][YSTR];                        // 33.1 KB
    __shared__ __align__(16) _Float16 hbuf[2][BM][HH];      // 8 KB
    __shared__ __align__(16) float pq[2][BM][PQS];          // 4.6 KB

    const int f = *(volatile const int*)flag;  // block-uniform
    if (f) rnn_body<true >(xg, h0, w0, b0, W, bw, dw, db, out, xs, ybuf, hbuf, pq);
    else   rnn_body<false>(xg, h0, w0, b0, W, bw, dw, db, out, xs, ybuf, hbuf, pq);
}

extern "C" void kernel_launch(void* const* d_in, const int* in_sizes, int n_in,
                              void* d_out, int out_size, void* d_ws, size_t ws_size,
                              hipStream_t stream) {
    int* flag = (int*)d_ws;
    detect_dtype<<<1, 64, 0, stream>>>(d_in[4], flag);  // probe fc_w
    rnn_mfma<<<BB / BM, 512, 0, stream>>>(d_in[0], d_in[1], d_in[2], d_in[3],
                                          d_in[4], d_in[5], d_in[6], d_in[7],
                                          d_out, flag);
}